// Round 13
// baseline (2512.749 us; speedup 1.0000x reference)
//
#include <hip/hip_runtime.h>

#define NPTS    2048
#define NBATCH  8
#define NPROB   24     // 8 batches x {xy, xx, yy}
#define NITER   30
#define TPB     512
#define WPB     8      // waves per block

// eps = 0.05, log-domain Sinkhorn in log2 space.
constexpr float KSC = 28.853900817779268f;   // log2(e)/eps
constexpr float C1f = 0.38123094930796995f;  // eps*ln(2048)
constexpr float C2f = 0.03465735902799726f;  // eps*ln(2)
// Exact identities: KSC*C1f = log2(2048) = 11, KSC*C2f = 1
//  => staged potential K*phi = 11 - log2(sum of per-slot partial sums)

typedef float v2f __attribute__((ext_vector_type(2)));   // row0 = .x, row1 = .y

__device__ __forceinline__ float fexp2(float x) { return __builtin_amdgcn_exp2f(x); }
__device__ __forceinline__ float flog2(float x) { return __builtin_amdgcn_logf(x); }
__device__ __forceinline__ float fsqrt(float x) { return __builtin_amdgcn_sqrtf(x); }

__global__ __launch_bounds__(256)
void init_sums(float* __restrict__ gsum, int n, float val)
{
    int i = blockIdx.x * 256 + threadIdx.x;
    if (i < n) gsum[i] = val;     // slots sum to 2048 -> K*phi0 = 0
}

__device__ __forceinline__ void problem_barrier(unsigned* arrive, unsigned* epoch,
                                                unsigned phase, int nbpp, int tid)
{
    __syncthreads();   // drain all waves' work before the release RMW
    if (tid == 0) {
        unsigned old = __hip_atomic_fetch_add(arrive, 1u, __ATOMIC_ACQ_REL,
                                              __HIP_MEMORY_SCOPE_AGENT);
        if (old == (unsigned)(nbpp - 1)) {
            __hip_atomic_store(arrive, 0u, __ATOMIC_RELAXED, __HIP_MEMORY_SCOPE_AGENT);
            __hip_atomic_store(epoch, phase, __ATOMIC_RELEASE, __HIP_MEMORY_SCOPE_AGENT);
        } else {
            while (__hip_atomic_load(epoch, __ATOMIC_RELAXED,
                                     __HIP_MEMORY_SCOPE_AGENT) < phase) {
                __builtin_amdgcn_s_sleep(2);
            }
            __threadfence();   // acquire: fresh sums visible to this CU
        }
    }
    __syncthreads();
}

__global__ __launch_bounds__(TPB, 8)   // 8 waves/EU -> 4 blocks/CU capacity
void sinkhorn_all(const float* __restrict__ xyz1,
                  const float* __restrict__ xyz2,
                  float* __restrict__ fsum,    // [NPROB][nq][NPTS] raw partial sums
                  float* __restrict__ gsum,    // [NPROB][nq][NPTS]
                  unsigned* __restrict__ bars,
                  int nbpp, int lognq)
{
    __shared__ float4 shC[1024];        // <=16 KB: {x,y,z,K*phi} cols of current job
    __shared__ float  shS[WPB][128];    // 4 KB: per-wave partials (2 rows/lane)

    const int nq    = 1 << lognq;          // column slots (4, fallback 2)
    const int njobs = 16 << lognq;         // 16 row-chunks x nq col-slices
    const int hc    = NPTS >> lognq;       // cols per job
    const int cpw   = hc >> 3;             // cols per wave

    const int tid  = threadIdx.x;
    const int lane = tid & 63;
    const int warp = tid >> 6;
    const int p    = blockIdx.x % NPROB;   // blocks of one problem share an XCD (24%8==0)
    const int lb   = blockIdx.x / NPROB;
    const int b    = p / 3;
    const int k    = p - 3 * b;            // 0: xy, 1: xx, 2: yy

    const float* xb = xyz1 + (size_t)b * NPTS * 3;
    const float* yb = xyz2 + (size_t)b * NPTS * 3;
    float* fS = fsum + (size_t)p * nq * NPTS;
    float* gS = gsum + (size_t)p * nq * NPTS;
    unsigned* arrive = bars + (size_t)p * 64;
    unsigned* epoch  = bars + (size_t)p * 64 + 32;

    // rows/cols of the f-update and g-update
    const float* Uf = (k == 2) ? yb : xb;
    const float* Ug = (k == 0) ? yb : ((k == 1) ? xb : yb);
    const float* Vf = (k == 1) ? xb : yb;
    const float* Vg = (k == 2) ? yb : xb;

    // stage col-slice q: coords (vectorized 3<->4 repack) + K*phi from raw sums
    auto stage = [&](const float* __restrict__ V, const float* __restrict__ S, int q) {
        const int nst = hc >> 2;               // staging threads, 4 cols each
        if (tid < nst) {
            const float4* V4 = (const float4*)V;   // 16B-aligned (24KB batch stride)
            const int g0 = q * hc + 4 * tid;       // global col of first staged col
            const int i0 = 3 * (g0 >> 2);
            const float4 a  = V4[i0 + 0];
            const float4 bb = V4[i0 + 1];
            const float4 cc = V4[i0 + 2];
            float4 ts = *(const float4*)(S + g0);
            for (int qq = 1; qq < nq; ++qq) {
                const float4 t = *(const float4*)(S + qq * NPTS + g0);
                ts.x += t.x; ts.y += t.y; ts.z += t.z; ts.w += t.w;
            }
            const int c = 4 * tid;                 // local col in job
            shC[c + 0] = make_float4(a.x,  a.y,  a.z,  11.0f - flog2(ts.x));
            shC[c + 1] = make_float4(a.w,  bb.x, bb.y, 11.0f - flog2(ts.y));
            shC[c + 2] = make_float4(bb.z, bb.w, cc.x, 11.0f - flog2(ts.z));
            shC[c + 3] = make_float4(cc.y, cc.z, cc.w, 11.0f - flog2(ts.w));
        }
    };

    // one job: 128 rows (2/lane, packed fp32) x this slice's hc cols
    auto do_pass = [&](const float* __restrict__ U, float* __restrict__ oS,
                       int q, int rc) {
        __syncthreads();                    // staging visible
        const int r0 = rc * 128 + lane, r1 = r0 + 64;
        const v2f ux = {U[3*r0],   U[3*r1]};
        const v2f uy = {U[3*r0+1], U[3*r1+1]};
        const v2f uz = {U[3*r0+2], U[3*r1+2]};
        const v2f e12 = {1e-12f, 1e-12f};
        const v2f nK  = {-KSC, -KSC};
        v2f s0 = {0.f, 0.f}, s1 = {0.f, 0.f}, s2 = {0.f, 0.f}, s3 = {0.f, 0.f};

        auto term = [&](const float4 v) -> v2f {
            v2f dx = ux - (v2f){v.x, v.x};
            v2f dy = uy - (v2f){v.y, v.y};
            v2f dz = uz - (v2f){v.z, v.z};
            v2f d2 = __builtin_elementwise_fma(dz, dz, e12);
            d2 = __builtin_elementwise_fma(dy, dy, d2);
            d2 = __builtin_elementwise_fma(dx, dx, d2);
            v2f sq  = {fsqrt(d2.x), fsqrt(d2.y)};
            v2f arg = __builtin_elementwise_fma(nK, sq, (v2f){v.w, v.w});
            return (v2f){fexp2(arg.x), fexp2(arg.y)};
        };
        const int cb = warp * cpw;
        #pragma unroll 2
        for (int c = cb; c < cb + cpw; c += 4) {
            const float4 v0 = shC[c + 0];
            const float4 v1 = shC[c + 1];
            const float4 v2 = shC[c + 2];
            const float4 v3 = shC[c + 3];
            s0 += term(v0);
            s1 += term(v1);
            s2 += term(v2);
            s3 += term(v3);
        }
        shS[warp][lane]      = (s0.x + s1.x) + (s2.x + s3.x);
        shS[warp][lane + 64] = (s0.y + s1.y) + (s2.y + s3.y);
        __syncthreads();
        if (tid < 128) {                    // merge 8 col-slices; write raw SUM
            float t = shS[0][tid];
            #pragma unroll
            for (int w = 1; w < WPB; ++w) t += shS[w][tid];
            oS[q * NPTS + rc * 128 + tid] = t;   // coalesced 512B, disjoint per job
        }
        __syncthreads();                    // shC/shS safe for the next job's stage
    };

    for (int it = 0; it < NITER; ++it) {
        // f-pass: rows Uf vs cols Vf, potential = g (raw sums), out = fS
        for (int j = lb; j < njobs; j += nbpp) {
            stage(Vf, gS, j & (nq - 1));
            do_pass(Uf, fS, j & (nq - 1), j >> lognq);
        }
        problem_barrier(arrive, epoch, (unsigned)(2 * it + 1), nbpp, tid);
        // g-pass: rows Ug vs cols Vg, potential = new f, out = gS
        for (int j = lb; j < njobs; j += nbpp) {
            stage(Vg, fS, j & (nq - 1));
            do_pass(Ug, gS, j & (nq - 1), j >> lognq);
        }
        problem_barrier(arrive, epoch, (unsigned)(2 * it + 2), nbpp, tid);
    }
    // no grid.sync: kernel end is the fence; reduce runs as a separate launch
}

__global__ __launch_bounds__(TPB, 1)
void final_reduce(const float* __restrict__ fsum, const float* __restrict__ gsum,
                  float* __restrict__ out, int lognq)
{
    __shared__ double red[WPB];
    const int nq   = 1 << lognq;
    const int tid  = threadIdx.x;
    const int lane = tid & 63;
    const int warp = tid >> 6;

    double acc = 0.0;
    for (int idx = tid; idx < 2 * NPROB * NPTS; idx += TPB) {
        const bool isF = idx < NPROB * NPTS;
        const int rem  = isF ? idx : idx - NPROB * NPTS;
        const int pp   = rem >> 11;            // / 2048
        const int j    = rem & (NPTS - 1);
        const float* S = (isF ? fsum : gsum) + (size_t)pp * nq * NPTS;
        float t = S[j];
        for (int q = 1; q < nq; ++q) t += S[q * NPTS + j];
        const float val = C1f - C2f * flog2(t);
        const float w   = (pp % 3 == 0) ? 1.0f : -0.5f;
        acc += (double)val * (double)w;
    }
    #pragma unroll
    for (int off = 32; off > 0; off >>= 1) acc += __shfl_xor(acc, off);
    if (lane == 0) red[warp] = acc;
    __syncthreads();
    if (warp == 0) {
        double v2 = (lane < WPB) ? red[lane] : 0.0;
        #pragma unroll
        for (int off = 32; off > 0; off >>= 1) v2 += __shfl_xor(v2, off);
        if (lane == 0) out[0] = (float)(v2 / (double)(NBATCH * NPTS));
    }
}

extern "C" void kernel_launch(void* const* d_in, const int* in_sizes, int n_in,
                              void* d_out, int out_size, void* d_ws, size_t ws_size,
                              hipStream_t stream)
{
    const float* xyz1 = (const float*)d_in[0];
    const float* xyz2 = (const float*)d_in[1];
    float* out = (float*)d_out;

    // nq=4 (quarter-col slots) if scratch allows; else proven nq=2 geometry
    size_t need4 = (size_t)NPROB * 4 * NPTS * sizeof(float) * 2
                 + (size_t)NPROB * 64 * sizeof(unsigned);
    int lognq = (ws_size >= need4) ? 2 : 1;
    int nq    = 1 << lognq;
    int njobs = 16 << lognq;

    float* fsum = (float*)d_ws;                        // [24][nq][2048]
    float* gsum = fsum + (size_t)NPROB * nq * NPTS;    // [24][nq][2048]
    unsigned* bars = (unsigned*)(gsum + (size_t)NPROB * nq * NPTS);

    // barrier state zero + g0 such that K*phi0 = 0 (deterministic per call)
    hipMemsetAsync(bars, 0, (size_t)NPROB * 64 * sizeof(unsigned), stream);
    int ninit = NPROB * nq * NPTS;
    init_sums<<<(ninit + 255) / 256, 256, 0, stream>>>(gsum, ninit,
                                                       (float)(NPTS / nq));

    // co-residency-safe grid: clamp to what the runtime will actually co-schedule
    int maxB = 0;
    hipOccupancyMaxActiveBlocksPerMultiprocessor(&maxB, sinkhorn_all, TPB, 0);
    if (maxB < 1) maxB = 1;
    int bpp = (maxB * 256) / NPROB;
    if (bpp > njobs) bpp = njobs;
    if (bpp < 1) bpp = 1;
    int nblk = NPROB * bpp;

    void* args[] = { (void*)&xyz1, (void*)&xyz2, (void*)&fsum, (void*)&gsum,
                     (void*)&bars, (void*)&bpp, (void*)&lognq };
    hipLaunchCooperativeKernel((void*)sinkhorn_all, dim3(nblk), dim3(TPB),
                               args, 0, stream);

    final_reduce<<<1, TPB, 0, stream>>>(fsum, gsum, out, lognq);
}